// Round 14
// baseline (108.193 us; speedup 1.0000x reference)
//
#include <hip/hip_runtime.h>

// Problem constants
#define MD 4
#define PATCH 9          // 2*MD+1
#define NZERO 1024       // zero-streaming blocks (FIRST in grid: start at fill-rate)
#define NBANDB 512       // band blocks: (b, ty, dy-half) = 4 * 64 * 2
#define BT 1024          // threads per block (16 waves)
// feat1/feat2: (4, 256, 64, 64) fp32
// out: (4, 4096, 64, 64) fp32 = 256 MB
//
// out[b, ty*64+tx, y, x] = sum_c f1[b,c,y,x] * f2[b,c,ty,tx]  if |ty-y|<=4 && |tx-x|<=4, else 0.
//
// Row partition: zero blocks write rows |y-ty|>4 (~220 MB, NT stores); band blocks write
// rows |y-ty|<=4 (~36 MB computed, NT stores). Band work split in dy-halves across TWO
// blocks per (b,ty) -> 512 band blocks, 2/CU co-residency (LDS 73.7 KB), 8 waves/SIMD in
// the band phase (R11 had 4). All output stores nontemporal: write-once stream must not
// thrash L2/LLC (FETCH=72MB vs 33.5MB inputs showed f1 being evicted between re-reads).

typedef float f4v __attribute__((ext_vector_type(4)));

__device__ __forceinline__ void nt_store4(float* p, float a, float b, float c, float d)
{
    f4v v = {a, b, c, d};
    __builtin_nontemporal_store(v, (f4v*)p);
}

template<int ND>
__device__ __forceinline__ void band_core(
    const float* __restrict__ f1base,     // f1 + (b*256 + cq*64)*4096 + lane
    const float (* __restrict__ sF2)[72], // this wave's 64 padded channel rows
    int ty, int dy0, int lane,
    float acc[2][PATCH])
{
    int yoff[ND];                          // clamped; invalid rows discarded at merge
#pragma unroll
    for (int i = 0; i < ND; ++i) {
        int y = ty + dy0 + i - MD;
        y = y < 0 ? 0 : (y > 63 ? 63 : y);
        yoff[i] = y * 64;
    }

    if constexpr (ND == 1) {
#pragma unroll 4
        for (int c = 0; c < 64; ++c) {
            const float* f1c = f1base + (size_t)c * 4096;
            float f1v = f1c[yoff[0]];                 // coalesced global load
            const float* wp = &sF2[c][lane];
            float sh[PATCH];
#pragma unroll
            for (int dxi = 0; dxi < PATCH; ++dxi)
                sh[dxi] = wp[8 - dxi];                // f2[c,ty,lane-dxi+4]; margins give 0
#pragma unroll
            for (int dxi = 0; dxi < PATCH; ++dxi)
                acc[0][dxi] = fmaf(f1v, sh[dxi], acc[0][dxi]);
        }
    } else {
#pragma unroll 2
        for (int c = 0; c < 64; ++c) {
            const float* f1c = f1base + (size_t)c * 4096;
            float f1v[ND];
#pragma unroll
            for (int i = 0; i < ND; ++i)
                f1v[i] = f1c[yoff[i]];
            const float* wp = &sF2[c][lane];
            float sh[PATCH];
#pragma unroll
            for (int dxi = 0; dxi < PATCH; ++dxi)
                sh[dxi] = wp[8 - dxi];
#pragma unroll
            for (int i = 0; i < ND; ++i)
#pragma unroll
                for (int dxi = 0; dxi < PATCH; ++dxi)
                    acc[i][dxi] = fmaf(f1v[i], sh[dxi], acc[i][dxi]);
        }
    }
}

// One dy-half of one (b,ty): HALF=0 -> dyi 0..3, HALF=1 -> dyi 4..8.
template<int HALF>
__device__ __forceinline__ void do_band(
    const float* __restrict__ f1, const float* __restrict__ f2,
    float* __restrict__ out, float* uLds, int b, int ty, int tid)
{
    constexpr int DY0 = HALF ? 4 : 0;
    constexpr int NR  = HALF ? 5 : 4;     // dy rows this block owns
    const int lane = tid & 63;
    const int w    = tid >> 6;            // 0..15
    const int cq   = w >> 2;              // channel quarter
    const int dyg  = w & 3;               // wave's dy slot
    const int dy0w = DY0 + dyg;           // HALF1 dyg3 -> rows 7,8
    const int nd   = (HALF && dyg == 3) ? 2 : 1;

    float (*sF2)[72] = (float(*)[72])uLds;

    // stage f2[b, c, ty, :] -> sF2[c][4..68), margins zeroed
    const float4* f2g = (const float4*)f2 + (size_t)(b * 256) * 1024 + ty * 16;
#pragma unroll
    for (int k = 0; k < 4; ++k) {
        int idx = k * BT + tid;           // 0..4095
        int cl = idx >> 4, x4 = idx & 15;
        *(float4*)&sF2[cl][4 + 4 * x4] = f2g[(size_t)cl * 1024 + x4];   // 16B-aligned
    }
    if (tid < 512) {
        int cl = tid >> 1, off = (tid & 1) ? 68 : 0;
        *(float4*)&sF2[cl][off] = make_float4(0.f, 0.f, 0.f, 0.f);
    }
    __syncthreads();

    float acc[2][PATCH];
#pragma unroll
    for (int i = 0; i < 2; ++i)
#pragma unroll
        for (int j = 0; j < PATCH; ++j) acc[i][j] = 0.f;

    const float* f1b = f1 + (size_t)(b * 256 + cq * 64) * 4096 + lane;
    const float (*sF2w)[72] = &sF2[cq * 64];

    if (HALF && dyg == 3) band_core<2>(f1b, sF2w, ty, dy0w, lane, acc);
    else                  band_core<1>(f1b, sF2w, ty, dy0w, lane, acc);

    __syncthreads();                      // all sF2 reads complete; uLds becomes sVals
    float (*sVals)[81] = (float(*)[81])uLds;   // sVals[tx][dyi*9+dxi]

    // Merge without zero-fill: cq==0 waves cover every entry of this half exactly once.
    if (cq == 0) {
#pragma unroll
        for (int i = 0; i < 2; ++i) {
            if (i >= nd) continue;        // wave-uniform
            int dyi = dy0w + i;
            int y = ty + dyi - MD;
            if ((unsigned)y >= 64u) continue;
#pragma unroll
            for (int dxi = 0; dxi < PATCH; ++dxi) {
                int tx = lane - (dxi - MD);
                if ((unsigned)tx < 64u)
                    sVals[tx][dyi * PATCH + dxi] = acc[i][dxi];   // stride 81: conflict-free
            }
        }
    }
    __syncthreads();
    if (cq != 0) {
#pragma unroll
        for (int i = 0; i < 2; ++i) {
            if (i >= nd) continue;
            int dyi = dy0w + i;
            int y = ty + dyi - MD;
            if ((unsigned)y >= 64u) continue;
#pragma unroll
            for (int dxi = 0; dxi < PATCH; ++dxi) {
                int tx = lane - (dxi - MD);
                if ((unsigned)tx < 64u)
                    atomicAdd(&sVals[tx][dyi * PATCH + dxi], acc[i][dxi]);
            }
        }
    }
    __syncthreads();

    // Writeout: this half's rows (dyi in [DY0, DY0+NR)), full 64-float rows, NT stores.
    float* outb = out + (size_t)(b * 4096 + ty * 64) * 4096;
    const int q4 = tid & 15;              // float4 index within a row
    const int ro = tid >> 4;              // 0..63
    for (int rb = 0; rb < 64 * NR; rb += 64) {
        int row = rb + ro;                // row = tx*NR + (dyi-DY0)
        int tx, dyi;
        if (NR == 4) { tx = row >> 2; dyi = DY0 + (row & 3); }
        else         { tx = row / 5;  dyi = DY0 + (row - 5 * tx); }
        int y = ty + dyi - MD;
        if ((unsigned)y < 64u) {
            float comp[4];
#pragma unroll
            for (int j = 0; j < 4; ++j) {
                int x  = q4 * 4 + j;
                int dx = x - tx;
                comp[j] = (dx >= -MD && dx <= MD) ? sVals[tx][dyi * PATCH + dx + MD] : 0.f;
            }
            nt_store4(outb + (size_t)tx * 4096 + y * 64 + q4 * 4,
                      comp[0], comp[1], comp[2], comp[3]);
        }
    }
}

__global__ __launch_bounds__(BT, 8) void cv_kernel(
    const float* __restrict__ f1,
    const float* __restrict__ f2,
    float* __restrict__ out)
{
    __shared__ float uLds[256 * 72];      // 73,728 B (band: sF2 then sVals; zero: unused)
    const int tid = threadIdx.x;

    // ---------------- zero-streaming blocks (first in dispatch order) ----------------
    if (blockIdx.x < NZERO) {
        // float4 index i: bits [0:4)=x4, [4:10)=y, [10:16)=tx, [16:22)=ty, [22:24)=b
        float* o = (float*)out;
        const int total4 = 4 * 4096 * 64 * 16;            // 16,777,216
        const int stride = NZERO * BT;
        for (int i = blockIdx.x * BT + tid; i < total4; i += stride) {
            int y  = (i >> 4) & 63;
            int ty = (i >> 16) & 63;
            int dy = y - ty;
            if (dy < -MD || dy > MD)
                nt_store4(o + (size_t)i * 4, 0.f, 0.f, 0.f, 0.f);
        }
        return;
    }

    // ---------------- band-compute blocks ----------------
    const int bb  = blockIdx.x - NZERO;   // 0..511
    const int bty = bb >> 1;              // 0..255
    const int b   = bty >> 6;
    const int ty  = bty & 63;

    if (bb & 1) do_band<1>(f1, f2, out, uLds, b, ty, tid);
    else        do_band<0>(f1, f2, out, uLds, b, ty, tid);
}

extern "C" void kernel_launch(void* const* d_in, const int* in_sizes, int n_in,
                              void* d_out, int out_size, void* d_ws, size_t ws_size,
                              hipStream_t stream) {
    const float* f1 = (const float*)d_in[0];
    const float* f2 = (const float*)d_in[1];
    float* out = (float*)d_out;
    cv_kernel<<<NZERO + NBANDB, BT, 0, stream>>>(f1, f2, out);
}